// Round 3
// baseline (410.650 us; speedup 1.0000x reference)
//
#include <hip/hip_runtime.h>
#include <hip/hip_bf16.h>
#include <math.h>

// ArcLoss: x[B,D] fp32, labels[B] int, W[C,D] fp32
// out = [cos_theta (B*C fp32), loss (1 fp32)]
// B=1024, D=512, C=50000 (D hard-assumed; B,C derived)

#define DD 512
#define TM 128
#define TN 128
#define TK 32
#define NSTEP (DD / TK)  // 16

typedef __attribute__((ext_vector_type(8))) short short8;
typedef __attribute__((ext_vector_type(4))) float f32x4;

// ---------------- Kernel 1: row-normalize x -> bf16, zero expsum ----------
__global__ __launch_bounds__(256) void arc_normalize_bf16(const float* __restrict__ x,
                                                          __hip_bfloat16* __restrict__ xn,
                                                          float* __restrict__ sumexp,
                                                          int B) {
    int r = blockIdx.x;
    int tid = threadIdx.x;
    const float* xr = x + (size_t)r * DD;
    float v0 = xr[tid];
    float v1 = xr[tid + 256];
    float ss = v0 * v0 + v1 * v1;
    #pragma unroll
    for (int off = 32; off > 0; off >>= 1) ss += __shfl_down(ss, off, 64);
    __shared__ float wsum[4];
    if ((tid & 63) == 0) wsum[tid >> 6] = ss;
    __syncthreads();
    float tot = wsum[0] + wsum[1] + wsum[2] + wsum[3];
    float inv = 1.0f / fmaxf(sqrtf(tot), 1e-12f);
    xn[(size_t)r * DD + tid] = __float2bfloat16(v0 * inv);
    xn[(size_t)r * DD + tid + 256] = __float2bfloat16(v1 * inv);
    if (tid == 0) sumexp[r] = 0.0f;
}

// ---------------- Kernel 2: fused MFMA GEMM -------------------------------
// cos = xn @ W^T, with W fp32 converted to bf16 IN-KERNEL (cvt_w eliminated).
// A (bf16) staged via global_load_lds; B (fp32 W) reg-staged: load->cvt->ds_write.
// 2-phase: double-buffered LDS, prefetch issued before MFMA, ONE barrier/K-step.
__global__ __launch_bounds__(256) void arc_gemm_fused(const __hip_bfloat16* __restrict__ A,
                                                      const float* __restrict__ W,
                                                      float* __restrict__ out,
                                                      float* __restrict__ sumexp,
                                                      int C) {
    __shared__ __hip_bfloat16 Als[2][TM * TK];  // 2 x 8 KB, [m][k] rows of 64 B
    __shared__ __hip_bfloat16 Bls[2][TN * TK];  // 2 x 8 KB, [n][k]

    const int tid = threadIdx.x;
    const int lane = tid & 63;
    const int wave = tid >> 6;
    const int quad = lane >> 4;
    const int l16 = lane & 15;
    const int wm = (wave >> 1) * 64;  // wave's m-offset in tile
    const int wn = (wave & 1) * 64;   // wave's n-offset in tile

    // T1: bijective XCD-chunked swizzle. Each XCD gets a contiguous chunk of
    // work ids (m fastest) -> 8 m-passes over one W-tile share that XCD's L2.
    // Round-2 evidence: FETCH 204 MB -> 30 MB. Keep.
    const int nwg = gridDim.x * gridDim.y;
    const int flat = blockIdx.x + gridDim.x * blockIdx.y;
    const int xcd = flat & 7;
    const int pos = flat >> 3;
    const int q = nwg >> 3;
    const int r8 = nwg & 7;
    const int wg = (xcd < r8 ? xcd * (q + 1) : r8 * (q + 1) + (xcd - r8) * q) + pos;
    const int m0 = (wg % gridDim.x) * TM;
    const int n0 = (wg / gridDim.x) * TN;

    f32x4 acc[4][4];
    #pragma unroll
    for (int i = 0; i < 4; i++)
        #pragma unroll
        for (int j = 0; j < 4; j++) acc[i][j] = (f32x4){0.f, 0.f, 0.f, 0.f};

    // A staging (global_load_lds): flat chunk f = tid; row=f>>2, kchunk=f&3;
    // LDS byte = f*16 = wave-uniform base + lane*16.
    const int rowA = tid >> 2, ch = tid & 3;
    const __hip_bfloat16* gA0 = A + (size_t)(m0 + rowA) * DD + ch * 8;
    const __hip_bfloat16* gA1 = gA0 + (size_t)64 * DD;

    // B staging (regs): thread t covers Bls rows t>>2 and 64+(t>>2),
    // k-chunk (t&3)*8. ds_write dest byte = t*16 (+4096): linear, conflict-free.
    const int rB = tid >> 2;
    const int kcB = (tid & 3) * 8;
    int nB0 = n0 + rB;       if (nB0 >= C) nB0 = C - 1;
    int nB1 = n0 + 64 + rB;  if (nB1 >= C) nB1 = C - 1;
    const float* gW0 = W + (size_t)nB0 * DD + kcB;
    const float* gW1 = W + (size_t)nB1 * DD + kcB;

    f32x4 b00, b01, b10, b11;  // in-flight fp32 B regs (16 VGPR)

#define ISSUE_A(t, buf)                                                              \
    do {                                                                             \
        char* d0_ = (char*)&Als[(buf)][0] + (tid & ~63) * 16;                        \
        __builtin_amdgcn_global_load_lds(                                            \
            (const __attribute__((address_space(1))) void*)(gA0 + (t) * TK),         \
            (__attribute__((address_space(3))) void*)d0_, 16, 0, 0);                 \
        __builtin_amdgcn_global_load_lds(                                            \
            (const __attribute__((address_space(1))) void*)(gA1 + (t) * TK),         \
            (__attribute__((address_space(3))) void*)(d0_ + 4096), 16, 0, 0);        \
    } while (0)

#define LOAD_B(t)                                                                    \
    do {                                                                             \
        const float* p0_ = gW0 + (t) * TK;                                           \
        const float* p1_ = gW1 + (t) * TK;                                           \
        b00 = *(const f32x4*)(p0_);                                                  \
        b01 = *(const f32x4*)(p0_ + 4);                                              \
        b10 = *(const f32x4*)(p1_);                                                  \
        b11 = *(const f32x4*)(p1_ + 4);                                              \
    } while (0)

#define WRITE_B(buf)                                                                 \
    do {                                                                             \
        union { __hip_bfloat16 h[8]; short8 v; } p0_, p1_;                           \
        p0_.h[0] = __float2bfloat16(b00.x); p0_.h[1] = __float2bfloat16(b00.y);      \
        p0_.h[2] = __float2bfloat16(b00.z); p0_.h[3] = __float2bfloat16(b00.w);      \
        p0_.h[4] = __float2bfloat16(b01.x); p0_.h[5] = __float2bfloat16(b01.y);      \
        p0_.h[6] = __float2bfloat16(b01.z); p0_.h[7] = __float2bfloat16(b01.w);      \
        p1_.h[0] = __float2bfloat16(b10.x); p1_.h[1] = __float2bfloat16(b10.y);      \
        p1_.h[2] = __float2bfloat16(b10.z); p1_.h[3] = __float2bfloat16(b10.w);      \
        p1_.h[4] = __float2bfloat16(b11.x); p1_.h[5] = __float2bfloat16(b11.y);      \
        p1_.h[6] = __float2bfloat16(b11.z); p1_.h[7] = __float2bfloat16(b11.w);      \
        *(short8*)((char*)&Bls[(buf)][0] + tid * 16) = p0_.v;                        \
        *(short8*)((char*)&Bls[(buf)][0] + tid * 16 + 4096) = p1_.v;                 \
    } while (0)

    // Prologue: stage K-step 0 into buffer 0.
    ISSUE_A(0, 0);
    LOAD_B(0);
    WRITE_B(0);        // compiler inserts vmcnt wait on b-reg use
    __syncthreads();   // drains gload_lds + ds_write: buffer 0 complete

    for (int t = 0; t < NSTEP; t++) {
        const int cur = t & 1, nxt = cur ^ 1;
        // Prefetch next K-step: issue loads BEFORE compute so latency hides
        // under ds_read+MFMA. A goes straight to LDS[nxt]; B lands in regs.
        if (t + 1 < NSTEP) {
            ISSUE_A(t + 1, nxt);
            LOAD_B(t + 1);
        }

        short8 af[4], bfr[4];
        #pragma unroll
        for (int mi = 0; mi < 4; mi++)
            af[mi] = *(const short8*)((const char*)&Als[cur][0] +
                                      ((wm + mi * 16 + l16) * TK + quad * 8) * 2);
        #pragma unroll
        for (int ni = 0; ni < 4; ni++)
            bfr[ni] = *(const short8*)((const char*)&Bls[cur][0] +
                                       ((wn + ni * 16 + l16) * TK + quad * 8) * 2);

        #pragma unroll
        for (int mi = 0; mi < 4; mi++)
            #pragma unroll
            for (int ni = 0; ni < 4; ni++)
                acc[mi][ni] = __builtin_amdgcn_mfma_f32_16x16x32_bf16(
                    af[mi], bfr[ni], acc[mi][ni], 0, 0, 0);

        // cvt + ds_write the prefetched B into LDS[nxt] (no reader conflicts).
        if (t + 1 < NSTEP) WRITE_B(nxt);
        __syncthreads();  // one barrier per K-step: nxt visible, cur free
    }

    // Epilogue: D layout row = quad*4+r (m side), col = l16 (n side).
    // Nontemporal stores keep the 205 MB output stream from evicting W in L2.
    const bool full = (n0 + TN <= C);
    #pragma unroll
    for (int mi = 0; mi < 4; mi++) {
        float se[4] = {0.f, 0.f, 0.f, 0.f};
        #pragma unroll
        for (int ni = 0; ni < 4; ni++) {
            int n = n0 + wn + ni * 16 + l16;
            f32x4 v = acc[mi][ni];
            if (full || n < C) {
                size_t base = (size_t)(m0 + wm + mi * 16 + quad * 4) * C + n;
                #pragma unroll
                for (int r = 0; r < 4; r++) {
                    __builtin_nontemporal_store(v[r], &out[base + (size_t)r * C]);
                    se[r] += expf(30.0f * v[r]);
                }
            }
        }
        #pragma unroll
        for (int off = 1; off < 16; off <<= 1) {
            #pragma unroll
            for (int r = 0; r < 4; r++) se[r] += __shfl_xor(se[r], off, 64);
        }
        if (l16 == 0) {
            int mbase = m0 + wm + mi * 16 + quad * 4;
            #pragma unroll
            for (int r = 0; r < 4; r++) atomicAdd(&sumexp[mbase + r], se[r]);
        }
    }
#undef ISSUE_A
#undef LOAD_B
#undef WRITE_B
}

// ---------------- fp32 fallback GEMM (used if ws too small) ---------------
#define BM 128
#define BN 128
#define BK 16
__global__ __launch_bounds__(256) void arc_normalize_f32(const float* __restrict__ x,
                                                         float* __restrict__ xn,
                                                         float* __restrict__ sumexp,
                                                         int B) {
    int r = blockIdx.x;
    int tid = threadIdx.x;
    const float* xr = x + (size_t)r * DD;
    float v0 = xr[tid];
    float v1 = xr[tid + 256];
    float ss = v0 * v0 + v1 * v1;
    #pragma unroll
    for (int off = 32; off > 0; off >>= 1) ss += __shfl_down(ss, off, 64);
    __shared__ float wsum[4];
    if ((tid & 63) == 0) wsum[tid >> 6] = ss;
    __syncthreads();
    float tot = wsum[0] + wsum[1] + wsum[2] + wsum[3];
    float inv = 1.0f / fmaxf(sqrtf(tot), 1e-12f);
    xn[(size_t)r * DD + tid] = v0 * inv;
    xn[(size_t)r * DD + tid + 256] = v1 * inv;
    if (tid == 0) sumexp[r] = 0.0f;
}

__global__ __launch_bounds__(256) void arc_gemm_f32(const float* __restrict__ A,
                                                    const float* __restrict__ Wm,
                                                    float* __restrict__ out,
                                                    float* __restrict__ sumexp,
                                                    int B, int C) {
    __shared__ float As[BK][BM];
    __shared__ float Bs[BK][BN];
    const int m0 = blockIdx.x * BM;
    const int n0 = blockIdx.y * BN;
    const int tid = threadIdx.x;
    const int tx = tid & 15;
    const int ty = tid >> 4;
    float acc[8][8];
    #pragma unroll
    for (int i = 0; i < 8; i++)
        #pragma unroll
        for (int j = 0; j < 8; j++) acc[i][j] = 0.0f;
    for (int k0 = 0; k0 < DD; k0 += BK) {
        #pragma unroll
        for (int l = 0; l < 2; l++) {
            int f = tid + l * 256;
            int row = f >> 2, kc = f & 3;
            float4 v = *(const float4*)(A + (size_t)(m0 + row) * DD + k0 + kc * 4);
            As[kc * 4 + 0][row] = v.x; As[kc * 4 + 1][row] = v.y;
            As[kc * 4 + 2][row] = v.z; As[kc * 4 + 3][row] = v.w;
        }
        #pragma unroll
        for (int l = 0; l < 2; l++) {
            int f = tid + l * 256;
            int row = f >> 2, kc = f & 3;
            int n = n0 + row;
            float4 v = make_float4(0.f, 0.f, 0.f, 0.f);
            if (n < C) v = *(const float4*)(Wm + (size_t)n * DD + k0 + kc * 4);
            Bs[kc * 4 + 0][row] = v.x; Bs[kc * 4 + 1][row] = v.y;
            Bs[kc * 4 + 2][row] = v.z; Bs[kc * 4 + 3][row] = v.w;
        }
        __syncthreads();
        #pragma unroll
        for (int k = 0; k < BK; k++) {
            float4 a0 = *(const float4*)&As[k][ty * 8];
            float4 a1 = *(const float4*)&As[k][ty * 8 + 4];
            float4 b0 = *(const float4*)&Bs[k][tx * 8];
            float4 b1 = *(const float4*)&Bs[k][tx * 8 + 4];
            float a[8] = {a0.x, a0.y, a0.z, a0.w, a1.x, a1.y, a1.z, a1.w};
            float b[8] = {b0.x, b0.y, b0.z, b0.w, b1.x, b1.y, b1.z, b1.w};
            #pragma unroll
            for (int i = 0; i < 8; i++)
                #pragma unroll
                for (int j = 0; j < 8; j++) acc[i][j] = fmaf(a[i], b[j], acc[i][j]);
        }
        __syncthreads();
    }
    const bool full = (n0 + BN <= C);
    #pragma unroll
    for (int i = 0; i < 8; i++) {
        int m = m0 + ty * 8 + i;
        float* orow = out + (size_t)m * C + n0 + tx * 8;
        float s = 0.0f;
        if (full) {
            *(float4*)orow = make_float4(acc[i][0], acc[i][1], acc[i][2], acc[i][3]);
            *(float4*)(orow + 4) = make_float4(acc[i][4], acc[i][5], acc[i][6], acc[i][7]);
            #pragma unroll
            for (int j = 0; j < 8; j++) s += expf(30.0f * acc[i][j]);
        } else {
            #pragma unroll
            for (int j = 0; j < 8; j++) {
                int n = n0 + tx * 8 + j;
                if (n < C) { orow[j] = acc[i][j]; s += expf(30.0f * acc[i][j]); }
            }
        }
        #pragma unroll
        for (int off = 1; off < 16; off <<= 1) s += __shfl_xor(s, off, 64);
        if (tx == 0) atomicAdd(&sumexp[m], s);
    }
}

// ---------------- Kernel 3: per-row loss + mean ---------------------------
__global__ __launch_bounds__(1024) void arc_finalize(const float* __restrict__ cosm,
                                                     const int* __restrict__ labels,
                                                     const float* __restrict__ sumexp,
                                                     float* __restrict__ out_loss,
                                                     int B, int C) {
    int r = threadIdx.x;
    float loss = 0.0f;
    if (r < B) {
        int lab = labels[r];
        float t_raw = cosm[(size_t)r * C + lab];
        float se = sumexp[r];
        float t = fminf(fmaxf(t_raw, -1.0f + 1e-7f), 1.0f - 1e-7f);
        const float cosM = 0.9210609940028851f;
        const float sinM = 0.3894183423086505f;
        float num = 30.0f * (t * cosM - sqrtf(fmaxf(1.0f - t * t, 0.0f)) * sinM);
        float excl = se - expf(30.0f * t_raw);
        float denom = expf(num) + excl;
        loss = num - logf(denom);
    }
    __shared__ float red[1024];
    red[threadIdx.x] = loss;
    __syncthreads();
    for (int s = 512; s > 0; s >>= 1) {
        if (threadIdx.x < s) red[threadIdx.x] += red[threadIdx.x + s];
        __syncthreads();
    }
    if (threadIdx.x == 0) out_loss[0] = -red[0] / (float)B;
}

extern "C" void kernel_launch(void* const* d_in, const int* in_sizes, int n_in,
                              void* d_out, int out_size, void* d_ws, size_t ws_size,
                              hipStream_t stream) {
    const float* x = (const float*)d_in[0];
    const int* labels = (const int*)d_in[1];
    const float* Wm = (const float*)d_in[2];
    int B = in_sizes[1];
    int C = in_sizes[2] / DD;
    float* out = (float*)d_out;

    size_t need = 4096 + (size_t)B * DD * 2 + 256;  // sumexp + xnb only (W read in-kernel)
    if (ws_size >= need) {
        // bf16 MFMA path (fused W conversion)
        float* sumexp = (float*)d_ws;                                 // B floats
        __hip_bfloat16* xnb = (__hip_bfloat16*)((char*)d_ws + 4096);  // B*DD bf16

        arc_normalize_bf16<<<B, 256, 0, stream>>>(x, xnb, sumexp, B);
        dim3 grid(B / TM, (C + TN - 1) / TN);
        arc_gemm_fused<<<grid, 256, 0, stream>>>(xnb, Wm, out, sumexp, C);
        arc_finalize<<<1, 1024, 0, stream>>>(out, labels, sumexp, out + (size_t)B * C, B, C);
    } else {
        // fp32 fallback
        float* xn = (float*)d_ws;
        float* sumexp = xn + (size_t)B * DD;
        arc_normalize_f32<<<B, 256, 0, stream>>>(x, xn, sumexp, B);
        dim3 grid(B / BM, (C + BN - 1) / BN);
        arc_gemm_f32<<<grid, 256, 0, stream>>>(xn, Wm, out, sumexp, B, C);
        arc_finalize<<<1, 1024, 0, stream>>>(out, labels, sumexp, out + (size_t)B * C, B, C);
    }
}

// Round 4
// 387.411 us; speedup vs baseline: 1.0600x; 1.0600x over previous
//
#include <hip/hip_runtime.h>
#include <hip/hip_bf16.h>
#include <math.h>

// ArcLoss: x[B,D] fp32, labels[B] int, W[C,D] fp32
// out = [cos_theta (B*C fp32), loss (1 fp32)]
// B=1024, D=512, C=50000 (D hard-assumed; B,C derived)

#define DD 512
#define TM 128
#define TN 128
#define TK 32
#define NSTEP (DD / TK)  // 16

typedef __attribute__((ext_vector_type(8))) short short8;
typedef __attribute__((ext_vector_type(4))) float f32x4;

// ---------------- Kernel 1: row-normalize x -> bf16, zero expsum ----------
__global__ __launch_bounds__(256) void arc_normalize_bf16(const float* __restrict__ x,
                                                          __hip_bfloat16* __restrict__ xn,
                                                          float* __restrict__ sumexp,
                                                          int B) {
    int r = blockIdx.x;
    int tid = threadIdx.x;
    const float* xr = x + (size_t)r * DD;
    float v0 = xr[tid];
    float v1 = xr[tid + 256];
    float ss = v0 * v0 + v1 * v1;
    #pragma unroll
    for (int off = 32; off > 0; off >>= 1) ss += __shfl_down(ss, off, 64);
    __shared__ float wsum[4];
    if ((tid & 63) == 0) wsum[tid >> 6] = ss;
    __syncthreads();
    float tot = wsum[0] + wsum[1] + wsum[2] + wsum[3];
    float inv = 1.0f / fmaxf(sqrtf(tot), 1e-12f);
    xn[(size_t)r * DD + tid] = __float2bfloat16(v0 * inv);
    xn[(size_t)r * DD + tid + 256] = __float2bfloat16(v1 * inv);
    if (tid == 0) sumexp[r] = 0.0f;
}

// ---------------- Kernel 2: W fp32 -> bf16 (round-2 proven version) -------
__global__ __launch_bounds__(256) void arc_cvt_w(const float* __restrict__ W,
                                                 __hip_bfloat16* __restrict__ Wb,
                                                 long n) {
    long i = ((long)blockIdx.x * 256 + threadIdx.x) * 8;
    if (i + 8 <= n) {
        // nontemporal: W fp32 is read exactly once per pass; don't pollute L2/LLC.
        f32x4 a = __builtin_nontemporal_load((const f32x4*)(W + i));
        f32x4 b = __builtin_nontemporal_load((const f32x4*)(W + i + 4));
        union { __hip_bfloat16 h[8]; short8 v; } pk;
        pk.h[0] = __float2bfloat16(a.x); pk.h[1] = __float2bfloat16(a.y);
        pk.h[2] = __float2bfloat16(a.z); pk.h[3] = __float2bfloat16(a.w);
        pk.h[4] = __float2bfloat16(b.x); pk.h[5] = __float2bfloat16(b.y);
        pk.h[6] = __float2bfloat16(b.z); pk.h[7] = __float2bfloat16(b.w);
        *(short8*)(Wb + i) = pk.v;
    } else if (i < n) {
        for (long j = i; j < n; j++) Wb[j] = __float2bfloat16(W[j]);
    }
}

// ---------------- Kernel 3: MFMA GEMM cos = xn @ W^T + fused exp-sum ------
// Round-4 structure: double-buffered LDS, global_load_lds prefetch issued
// AFTER the barrier (next buffer), ONE __syncthreads per K-step. The barrier's
// implicit vmcnt(0) then drains loads issued a full MFMA-phase earlier ->
// L2 latency hidden instead of exposed (round-2 was 2 barriers, same-step drain).
__global__ __launch_bounds__(256) void arc_gemm_mfma(const __hip_bfloat16* __restrict__ A,
                                                     const __hip_bfloat16* __restrict__ Wb,
                                                     float* __restrict__ out,
                                                     float* __restrict__ sumexp,
                                                     int C) {
    __shared__ __hip_bfloat16 Als[2][TM * TK];  // 2 x 8 KB, [m][k] rows of 64 B
    __shared__ __hip_bfloat16 Bls[2][TN * TK];  // 2 x 8 KB, [n][k]

    const int tid = threadIdx.x;
    const int lane = tid & 63;
    const int wave = tid >> 6;
    const int quad = lane >> 4;
    const int l16 = lane & 15;
    const int wm = (wave >> 1) * 64;  // wave's m-offset in tile
    const int wn = (wave & 1) * 64;   // wave's n-offset in tile

    // T1: bijective XCD-chunked swizzle. Each XCD gets a contiguous chunk of
    // work ids (m fastest) -> 8 m-passes over one W-tile share that XCD's L2.
    // Round-2 evidence: FETCH 204 MB -> 30 MB. Keep.
    const int nwg = gridDim.x * gridDim.y;
    const int flat = blockIdx.x + gridDim.x * blockIdx.y;
    const int xcd = flat & 7;
    const int pos = flat >> 3;
    const int q = nwg >> 3;
    const int r8 = nwg & 7;
    const int wg = (xcd < r8 ? xcd * (q + 1) : r8 * (q + 1) + (xcd - r8) * q) + pos;
    const int m0 = (wg % gridDim.x) * TM;
    const int n0 = (wg / gridDim.x) * TN;

    f32x4 acc[4][4];
    #pragma unroll
    for (int i = 0; i < 4; i++)
        #pragma unroll
        for (int j = 0; j < 4; j++) acc[i][j] = (f32x4){0.f, 0.f, 0.f, 0.f};

    // Staging: flat chunk f = tid; row = f>>2, kchunk = f&3.
    // LDS byte addr = f*16 == wave_uniform_base + lane*16  (fits global_load_lds)
    const int rowA = tid >> 2, ch = tid & 3;
    const __hip_bfloat16* gA0 = A + (size_t)(m0 + rowA) * DD + ch * 8;
    const __hip_bfloat16* gA1 = gA0 + (size_t)64 * DD;
    int nr0 = n0 + rowA;      if (nr0 >= C) nr0 = C - 1;
    int nr1 = n0 + 64 + rowA; if (nr1 >= C) nr1 = C - 1;
    const __hip_bfloat16* gB0 = Wb + (size_t)nr0 * DD + ch * 8;
    const __hip_bfloat16* gB1 = Wb + (size_t)nr1 * DD + ch * 8;

    const int ldsOff = (tid & ~63) * 16;  // wave-uniform base + lane*16

#define ISSUE(t, buf)                                                                \
    do {                                                                             \
        char* dA_ = (char*)&Als[(buf)][0] + ldsOff;                                  \
        char* dB_ = (char*)&Bls[(buf)][0] + ldsOff;                                  \
        __builtin_amdgcn_global_load_lds(                                            \
            (const __attribute__((address_space(1))) void*)(gA0 + (t) * TK),         \
            (__attribute__((address_space(3))) void*)dA_, 16, 0, 0);                 \
        __builtin_amdgcn_global_load_lds(                                            \
            (const __attribute__((address_space(1))) void*)(gA1 + (t) * TK),         \
            (__attribute__((address_space(3))) void*)(dA_ + 4096), 16, 0, 0);        \
        __builtin_amdgcn_global_load_lds(                                            \
            (const __attribute__((address_space(1))) void*)(gB0 + (t) * TK),         \
            (__attribute__((address_space(3))) void*)dB_, 16, 0, 0);                 \
        __builtin_amdgcn_global_load_lds(                                            \
            (const __attribute__((address_space(1))) void*)(gB1 + (t) * TK),         \
            (__attribute__((address_space(3))) void*)(dB_ + 4096), 16, 0, 0);        \
    } while (0)

    // Prologue: stage K-step 0 into buffer 0.
    ISSUE(0, 0);

    for (int t = 0; t < NSTEP; t++) {
        const int cur = t & 1, nxt = cur ^ 1;
        // Barrier top-of-step: implicit vmcnt(0) drains buf[cur]'s loads,
        // issued one full MFMA-phase ago (prologue for t=0). Also guarantees
        // all waves finished reading buf[nxt] (they did so before this
        // barrier, in iteration t-1) -> safe to overwrite it below.
        __syncthreads();

        // Prefetch next K-step into the other buffer; stays in flight across
        // the whole ds_read+MFMA phase below (drained by next barrier).
        if (t + 1 < NSTEP) ISSUE(t + 1, nxt);

        short8 af[4], bfr[4];
        #pragma unroll
        for (int mi = 0; mi < 4; mi++)
            af[mi] = *(const short8*)((const char*)&Als[cur][0] +
                                      ((wm + mi * 16 + l16) * TK + quad * 8) * 2);
        #pragma unroll
        for (int ni = 0; ni < 4; ni++)
            bfr[ni] = *(const short8*)((const char*)&Bls[cur][0] +
                                       ((wn + ni * 16 + l16) * TK + quad * 8) * 2);

        #pragma unroll
        for (int mi = 0; mi < 4; mi++)
            #pragma unroll
            for (int ni = 0; ni < 4; ni++)
                acc[mi][ni] = __builtin_amdgcn_mfma_f32_16x16x32_bf16(
                    af[mi], bfr[ni], acc[mi][ni], 0, 0, 0);
    }
#undef ISSUE

    // Epilogue: D layout row = quad*4+r (m side), col = l16 (n side).
    // Regular (cached) stores: L2 merges the two 64 B half-lines per 128 B
    // line (adjacent ni) -> expect WRITE_SIZE back to ~215 MB (was 284 NT).
    const bool full = (n0 + TN <= C);
    #pragma unroll
    for (int mi = 0; mi < 4; mi++) {
        float se[4] = {0.f, 0.f, 0.f, 0.f};
        #pragma unroll
        for (int ni = 0; ni < 4; ni++) {
            int n = n0 + wn + ni * 16 + l16;
            f32x4 v = acc[mi][ni];
            if (full || n < C) {
                size_t base = (size_t)(m0 + wm + mi * 16 + quad * 4) * C + n;
                #pragma unroll
                for (int r = 0; r < 4; r++) {
                    out[base + (size_t)r * C] = v[r];
                    se[r] += expf(30.0f * v[r]);
                }
            }
        }
        #pragma unroll
        for (int off = 1; off < 16; off <<= 1) {
            #pragma unroll
            for (int r = 0; r < 4; r++) se[r] += __shfl_xor(se[r], off, 64);
        }
        if (l16 == 0) {
            int mbase = m0 + wm + mi * 16 + quad * 4;
            #pragma unroll
            for (int r = 0; r < 4; r++) atomicAdd(&sumexp[mbase + r], se[r]);
        }
    }
}

// ---------------- fp32 fallback GEMM (used if ws too small) ---------------
#define BM 128
#define BN 128
#define BK 16
__global__ __launch_bounds__(256) void arc_normalize_f32(const float* __restrict__ x,
                                                         float* __restrict__ xn,
                                                         float* __restrict__ sumexp,
                                                         int B) {
    int r = blockIdx.x;
    int tid = threadIdx.x;
    const float* xr = x + (size_t)r * DD;
    float v0 = xr[tid];
    float v1 = xr[tid + 256];
    float ss = v0 * v0 + v1 * v1;
    #pragma unroll
    for (int off = 32; off > 0; off >>= 1) ss += __shfl_down(ss, off, 64);
    __shared__ float wsum[4];
    if ((tid & 63) == 0) wsum[tid >> 6] = ss;
    __syncthreads();
    float tot = wsum[0] + wsum[1] + wsum[2] + wsum[3];
    float inv = 1.0f / fmaxf(sqrtf(tot), 1e-12f);
    xn[(size_t)r * DD + tid] = v0 * inv;
    xn[(size_t)r * DD + tid + 256] = v1 * inv;
    if (tid == 0) sumexp[r] = 0.0f;
}

__global__ __launch_bounds__(256) void arc_gemm_f32(const float* __restrict__ A,
                                                    const float* __restrict__ Wm,
                                                    float* __restrict__ out,
                                                    float* __restrict__ sumexp,
                                                    int B, int C) {
    __shared__ float As[BK][BM];
    __shared__ float Bs[BK][BN];
    const int m0 = blockIdx.x * BM;
    const int n0 = blockIdx.y * BN;
    const int tid = threadIdx.x;
    const int tx = tid & 15;
    const int ty = tid >> 4;
    float acc[8][8];
    #pragma unroll
    for (int i = 0; i < 8; i++)
        #pragma unroll
        for (int j = 0; j < 8; j++) acc[i][j] = 0.0f;
    for (int k0 = 0; k0 < DD; k0 += BK) {
        #pragma unroll
        for (int l = 0; l < 2; l++) {
            int f = tid + l * 256;
            int row = f >> 2, kc = f & 3;
            float4 v = *(const float4*)(A + (size_t)(m0 + row) * DD + k0 + kc * 4);
            As[kc * 4 + 0][row] = v.x; As[kc * 4 + 1][row] = v.y;
            As[kc * 4 + 2][row] = v.z; As[kc * 4 + 3][row] = v.w;
        }
        #pragma unroll
        for (int l = 0; l < 2; l++) {
            int f = tid + l * 256;
            int row = f >> 2, kc = f & 3;
            int n = n0 + row;
            float4 v = make_float4(0.f, 0.f, 0.f, 0.f);
            if (n < C) v = *(const float4*)(Wm + (size_t)n * DD + k0 + kc * 4);
            Bs[kc * 4 + 0][row] = v.x; Bs[kc * 4 + 1][row] = v.y;
            Bs[kc * 4 + 2][row] = v.z; Bs[kc * 4 + 3][row] = v.w;
        }
        __syncthreads();
        #pragma unroll
        for (int k = 0; k < BK; k++) {
            float4 a0 = *(const float4*)&As[k][ty * 8];
            float4 a1 = *(const float4*)&As[k][ty * 8 + 4];
            float4 b0 = *(const float4*)&Bs[k][tx * 8];
            float4 b1 = *(const float4*)&Bs[k][tx * 8 + 4];
            float a[8] = {a0.x, a0.y, a0.z, a0.w, a1.x, a1.y, a1.z, a1.w};
            float b[8] = {b0.x, b0.y, b0.z, b0.w, b1.x, b1.y, b1.z, b1.w};
            #pragma unroll
            for (int i = 0; i < 8; i++)
                #pragma unroll
                for (int j = 0; j < 8; j++) acc[i][j] = fmaf(a[i], b[j], acc[i][j]);
        }
        __syncthreads();
    }
    const bool full = (n0 + BN <= C);
    #pragma unroll
    for (int i = 0; i < 8; i++) {
        int m = m0 + ty * 8 + i;
        float* orow = out + (size_t)m * C + n0 + tx * 8;
        float s = 0.0f;
        if (full) {
            *(float4*)orow = make_float4(acc[i][0], acc[i][1], acc[i][2], acc[i][3]);
            *(float4*)(orow + 4) = make_float4(acc[i][4], acc[i][5], acc[i][6], acc[i][7]);
            #pragma unroll
            for (int j = 0; j < 8; j++) s += expf(30.0f * acc[i][j]);
        } else {
            #pragma unroll
            for (int j = 0; j < 8; j++) {
                int n = n0 + tx * 8 + j;
                if (n < C) { orow[j] = acc[i][j]; s += expf(30.0f * acc[i][j]); }
            }
        }
        #pragma unroll
        for (int off = 1; off < 16; off <<= 1) s += __shfl_xor(s, off, 64);
        if (tx == 0) atomicAdd(&sumexp[m], s);
    }
}

// ---------------- Kernel 4: per-row loss + mean ---------------------------
__global__ __launch_bounds__(1024) void arc_finalize(const float* __restrict__ cosm,
                                                     const int* __restrict__ labels,
                                                     const float* __restrict__ sumexp,
                                                     float* __restrict__ out_loss,
                                                     int B, int C) {
    int r = threadIdx.x;
    float loss = 0.0f;
    if (r < B) {
        int lab = labels[r];
        float t_raw = cosm[(size_t)r * C + lab];
        float se = sumexp[r];
        float t = fminf(fmaxf(t_raw, -1.0f + 1e-7f), 1.0f - 1e-7f);
        const float cosM = 0.9210609940028851f;
        const float sinM = 0.3894183423086505f;
        float num = 30.0f * (t * cosM - sqrtf(fmaxf(1.0f - t * t, 0.0f)) * sinM);
        float excl = se - expf(30.0f * t_raw);
        float denom = expf(num) + excl;
        loss = num - logf(denom);
    }
    __shared__ float red[1024];
    red[threadIdx.x] = loss;
    __syncthreads();
    for (int s = 512; s > 0; s >>= 1) {
        if (threadIdx.x < s) red[threadIdx.x] += red[threadIdx.x + s];
        __syncthreads();
    }
    if (threadIdx.x == 0) out_loss[0] = -red[0] / (float)B;
}

extern "C" void kernel_launch(void* const* d_in, const int* in_sizes, int n_in,
                              void* d_out, int out_size, void* d_ws, size_t ws_size,
                              hipStream_t stream) {
    const float* x = (const float*)d_in[0];
    const int* labels = (const int*)d_in[1];
    const float* Wm = (const float*)d_in[2];
    int B = in_sizes[1];
    int C = in_sizes[2] / DD;
    float* out = (float*)d_out;

    size_t need = 4096 + (size_t)B * DD * 2 + (size_t)C * DD * 2 + 256;
    if (ws_size >= need) {
        // bf16 MFMA path
        float* sumexp = (float*)d_ws;                                    // B floats (<=4KB)
        __hip_bfloat16* xnb = (__hip_bfloat16*)((char*)d_ws + 4096);     // B*DD bf16
        __hip_bfloat16* Wb = xnb + (size_t)B * DD;                       // C*DD bf16

        arc_normalize_bf16<<<B, 256, 0, stream>>>(x, xnb, sumexp, B);
        long wn = (long)C * DD;
        long nblk = (wn / 8 + 255) / 256;
        arc_cvt_w<<<(int)nblk, 256, 0, stream>>>(Wm, Wb, wn);
        dim3 grid(B / TM, (C + TN - 1) / TN);
        arc_gemm_mfma<<<grid, 256, 0, stream>>>(xnb, Wb, out, sumexp, C);
        arc_finalize<<<1, 1024, 0, stream>>>(out, labels, sumexp, out + (size_t)B * C, B, C);
    } else {
        // fp32 fallback
        float* xn = (float*)d_ws;
        float* sumexp = xn + (size_t)B * DD;
        arc_normalize_f32<<<B, 256, 0, stream>>>(x, xn, sumexp, B);
        dim3 grid(B / BM, (C + BN - 1) / BN);
        arc_gemm_f32<<<grid, 256, 0, stream>>>(xn, Wm, out, sumexp, B, C);
        arc_finalize<<<1, 1024, 0, stream>>>(out, labels, sumexp, out + (size_t)B * C, B, C);
    }
}

// Round 5
// 368.738 us; speedup vs baseline: 1.1137x; 1.0506x over previous
//
#include <hip/hip_runtime.h>
#include <hip/hip_bf16.h>
#include <math.h>

// ArcLoss: x[B,D] fp32, labels[B] int, W[C,D] fp32
// out = [cos_theta (B*C fp32), loss (1 fp32)]
// B=1024, D=512, C=50000 (D hard-assumed; B,C derived)

#define DD 512
#define TM 128
#define TN 128
#define TK 32
#define NSTEP (DD / TK)  // 16

typedef __attribute__((ext_vector_type(8))) short short8;
typedef __attribute__((ext_vector_type(4))) float f32x4;

// ---------------- Kernel 1: row-normalize x -> bf16, zero expsum ----------
__global__ __launch_bounds__(256) void arc_normalize_bf16(const float* __restrict__ x,
                                                          __hip_bfloat16* __restrict__ xn,
                                                          float* __restrict__ sumexp,
                                                          int B) {
    int r = blockIdx.x;
    int tid = threadIdx.x;
    const float* xr = x + (size_t)r * DD;
    float v0 = xr[tid];
    float v1 = xr[tid + 256];
    float ss = v0 * v0 + v1 * v1;
    #pragma unroll
    for (int off = 32; off > 0; off >>= 1) ss += __shfl_down(ss, off, 64);
    __shared__ float wsum[4];
    if ((tid & 63) == 0) wsum[tid >> 6] = ss;
    __syncthreads();
    float tot = wsum[0] + wsum[1] + wsum[2] + wsum[3];
    float inv = 1.0f / fmaxf(sqrtf(tot), 1e-12f);
    xn[(size_t)r * DD + tid] = __float2bfloat16(v0 * inv);
    xn[(size_t)r * DD + tid + 256] = __float2bfloat16(v1 * inv);
    if (tid == 0) sumexp[r] = 0.0f;
}

// ---------------- Kernel 2: W fp32 -> bf16 --------------------------------
__global__ __launch_bounds__(256) void arc_cvt_w(const float* __restrict__ W,
                                                 __hip_bfloat16* __restrict__ Wb,
                                                 long n) {
    long i = ((long)blockIdx.x * 256 + threadIdx.x) * 8;
    if (i + 8 <= n) {
        // nontemporal: W fp32 is read exactly once per pass; don't pollute L2/LLC.
        f32x4 a = __builtin_nontemporal_load((const f32x4*)(W + i));
        f32x4 b = __builtin_nontemporal_load((const f32x4*)(W + i + 4));
        union { __hip_bfloat16 h[8]; short8 v; } pk;
        pk.h[0] = __float2bfloat16(a.x); pk.h[1] = __float2bfloat16(a.y);
        pk.h[2] = __float2bfloat16(a.z); pk.h[3] = __float2bfloat16(a.w);
        pk.h[4] = __float2bfloat16(b.x); pk.h[5] = __float2bfloat16(b.y);
        pk.h[6] = __float2bfloat16(b.z); pk.h[7] = __float2bfloat16(b.w);
        *(short8*)(Wb + i) = pk.v;
    } else if (i < n) {
        for (long j = i; j < n; j++) Wb[j] = __float2bfloat16(W[j]);
    }
}

// ---------------- Kernel 3: MFMA GEMM cos = xn @ W^T + fused exp-sum ------
// Round-5 structure (T3+T4): 3 LDS buffers, prefetch depth 2, counted
// s_waitcnt vmcnt(4) + raw s_barrier per K-step. Step t's staging loads were
// issued TWO phases earlier; t+1's 4 loads stay in flight across the barrier
// (never drain to 0 in the main loop). Round-4 had implicit vmcnt(0)/barrier
// with 1-phase prefetch -> L2 latency partially exposed (MfmaUtil 16%).
__global__ __launch_bounds__(256) void arc_gemm_mfma(const __hip_bfloat16* __restrict__ A,
                                                     const __hip_bfloat16* __restrict__ Wb,
                                                     float* __restrict__ out,
                                                     float* __restrict__ sumexp,
                                                     int C) {
    // 3 buffers x 16 KB: A tile at +0 (8 KB), B tile at +8192 (8 KB).
    __shared__ char lds[3][16384];

    const int tid = threadIdx.x;
    const int lane = tid & 63;
    const int wave = tid >> 6;
    const int quad = lane >> 4;
    const int l16 = lane & 15;
    const int wm = (wave >> 1) * 64;  // wave's m-offset in tile
    const int wn = (wave & 1) * 64;   // wave's n-offset in tile

    // T1: bijective XCD-chunked swizzle. Round-2 evidence: FETCH 204->30 MB. Keep.
    const int nwg = gridDim.x * gridDim.y;
    const int flat = blockIdx.x + gridDim.x * blockIdx.y;
    const int xcd = flat & 7;
    const int pos = flat >> 3;
    const int q = nwg >> 3;
    const int r8 = nwg & 7;
    const int wg = (xcd < r8 ? xcd * (q + 1) : r8 * (q + 1) + (xcd - r8) * q) + pos;
    const int m0 = (wg % gridDim.x) * TM;
    const int n0 = (wg / gridDim.x) * TN;

    f32x4 acc[4][4];
    #pragma unroll
    for (int i = 0; i < 4; i++)
        #pragma unroll
        for (int j = 0; j < 4; j++) acc[i][j] = (f32x4){0.f, 0.f, 0.f, 0.f};

    // Staging: flat chunk f = tid; row = f>>2, kchunk = f&3.
    // LDS byte addr = f*16 == wave_uniform_base + lane*16  (fits global_load_lds)
    const int rowA = tid >> 2, ch = tid & 3;
    const __hip_bfloat16* gA0 = A + (size_t)(m0 + rowA) * DD + ch * 8;
    const __hip_bfloat16* gA1 = gA0 + (size_t)64 * DD;
    int nr0 = n0 + rowA;      if (nr0 >= C) nr0 = C - 1;
    int nr1 = n0 + 64 + rowA; if (nr1 >= C) nr1 = C - 1;
    const __hip_bfloat16* gB0 = Wb + (size_t)nr0 * DD + ch * 8;
    const __hip_bfloat16* gB1 = Wb + (size_t)nr1 * DD + ch * 8;

    const int ldsOff = (tid & ~63) * 16;  // wave-uniform base; HW adds lane*16

#define ISSUE(t, bufbase)                                                            \
    do {                                                                             \
        char* dA_ = (bufbase) + ldsOff;                                              \
        char* dB_ = (bufbase) + 8192 + ldsOff;                                       \
        __builtin_amdgcn_global_load_lds(                                            \
            (const __attribute__((address_space(1))) void*)(gA0 + (t) * TK),         \
            (__attribute__((address_space(3))) void*)dA_, 16, 0, 0);                 \
        __builtin_amdgcn_global_load_lds(                                            \
            (const __attribute__((address_space(1))) void*)(gA1 + (t) * TK),         \
            (__attribute__((address_space(3))) void*)(dA_ + 4096), 16, 0, 0);        \
        __builtin_amdgcn_global_load_lds(                                            \
            (const __attribute__((address_space(1))) void*)(gB0 + (t) * TK),         \
            (__attribute__((address_space(3))) void*)dB_, 16, 0, 0);                 \
        __builtin_amdgcn_global_load_lds(                                            \
            (const __attribute__((address_space(1))) void*)(gB1 + (t) * TK),         \
            (__attribute__((address_space(3))) void*)(dB_ + 4096), 16, 0, 0);        \
    } while (0)

    // Prologue: stage K-steps 0,1 into buffers 0,1 (8 loads in flight).
    ISSUE(0, &lds[0][0]);
    ISSUE(1, &lds[1][0]);

    int ib = 0;  // t % 3, maintained incrementally (no div)
    for (int t = 0; t < NSTEP; t++) {
        // Own step-t loads done (allow t+1's 4 to remain in flight). Loads
        // retire in order, so vmcnt(4) waits exactly for the 4 oldest (= t's).
        if (t == NSTEP - 1)
            asm volatile("s_waitcnt vmcnt(0)" ::: "memory");
        else
            asm volatile("s_waitcnt vmcnt(4)" ::: "memory");
        // All waves: (a) past their step t-1 ds_reads (so buf[(t+2)%3], last
        // read at t-1, is safe to overwrite), (b) past their vmcnt -> all
        // waves' step-t staging is visible in LDS.
        __builtin_amdgcn_s_barrier();
        __builtin_amdgcn_sched_barrier(0);  // pin: no ds_read hoists above barrier

        int ip = ib + 2; if (ip >= 3) ip -= 3;          // (t+2) % 3
        if (t + 2 < NSTEP) ISSUE(t + 2, &lds[ip][0]);

        const char* base = &lds[ib][0];
        short8 af[4], bfr[4];
        #pragma unroll
        for (int mi = 0; mi < 4; mi++)
            af[mi] = *(const short8*)(base + (wm + mi * 16 + l16) * 64 + quad * 16);
        #pragma unroll
        for (int ni = 0; ni < 4; ni++)
            bfr[ni] = *(const short8*)(base + 8192 + (wn + ni * 16 + l16) * 64 + quad * 16);

        #pragma unroll
        for (int mi = 0; mi < 4; mi++)
            #pragma unroll
            for (int ni = 0; ni < 4; ni++)
                acc[mi][ni] = __builtin_amdgcn_mfma_f32_16x16x32_bf16(
                    af[mi], bfr[ni], acc[mi][ni], 0, 0, 0);

        ib++; if (ib >= 3) ib -= 3;
    }
#undef ISSUE

    // Epilogue: D layout row = quad*4+r (m side), col = l16 (n side).
    // Regular (cached) stores: L2 merges half-lines (round-4: WRITE 284->215 MB).
    const bool full = (n0 + TN <= C);
    #pragma unroll
    for (int mi = 0; mi < 4; mi++) {
        float se[4] = {0.f, 0.f, 0.f, 0.f};
        #pragma unroll
        for (int ni = 0; ni < 4; ni++) {
            int n = n0 + wn + ni * 16 + l16;
            f32x4 v = acc[mi][ni];
            if (full || n < C) {
                size_t base = (size_t)(m0 + wm + mi * 16 + quad * 4) * C + n;
                #pragma unroll
                for (int r = 0; r < 4; r++) {
                    out[base + (size_t)r * C] = v[r];
                    se[r] += expf(30.0f * v[r]);
                }
            }
        }
        #pragma unroll
        for (int off = 1; off < 16; off <<= 1) {
            #pragma unroll
            for (int r = 0; r < 4; r++) se[r] += __shfl_xor(se[r], off, 64);
        }
        if (l16 == 0) {
            int mbase = m0 + wm + mi * 16 + quad * 4;
            #pragma unroll
            for (int r = 0; r < 4; r++) atomicAdd(&sumexp[mbase + r], se[r]);
        }
    }
}

// ---------------- fp32 fallback GEMM (used if ws too small) ---------------
#define BM 128
#define BN 128
#define BK 16
__global__ __launch_bounds__(256) void arc_normalize_f32(const float* __restrict__ x,
                                                         float* __restrict__ xn,
                                                         float* __restrict__ sumexp,
                                                         int B) {
    int r = blockIdx.x;
    int tid = threadIdx.x;
    const float* xr = x + (size_t)r * DD;
    float v0 = xr[tid];
    float v1 = xr[tid + 256];
    float ss = v0 * v0 + v1 * v1;
    #pragma unroll
    for (int off = 32; off > 0; off >>= 1) ss += __shfl_down(ss, off, 64);
    __shared__ float wsum[4];
    if ((tid & 63) == 0) wsum[tid >> 6] = ss;
    __syncthreads();
    float tot = wsum[0] + wsum[1] + wsum[2] + wsum[3];
    float inv = 1.0f / fmaxf(sqrtf(tot), 1e-12f);
    xn[(size_t)r * DD + tid] = v0 * inv;
    xn[(size_t)r * DD + tid + 256] = v1 * inv;
    if (tid == 0) sumexp[r] = 0.0f;
}

__global__ __launch_bounds__(256) void arc_gemm_f32(const float* __restrict__ A,
                                                    const float* __restrict__ Wm,
                                                    float* __restrict__ out,
                                                    float* __restrict__ sumexp,
                                                    int B, int C) {
    __shared__ float As[BK][BM];
    __shared__ float Bs[BK][BN];
    const int m0 = blockIdx.x * BM;
    const int n0 = blockIdx.y * BN;
    const int tid = threadIdx.x;
    const int tx = tid & 15;
    const int ty = tid >> 4;
    float acc[8][8];
    #pragma unroll
    for (int i = 0; i < 8; i++)
        #pragma unroll
        for (int j = 0; j < 8; j++) acc[i][j] = 0.0f;
    for (int k0 = 0; k0 < DD; k0 += BK) {
        #pragma unroll
        for (int l = 0; l < 2; l++) {
            int f = tid + l * 256;
            int row = f >> 2, kc = f & 3;
            float4 v = *(const float4*)(A + (size_t)(m0 + row) * DD + k0 + kc * 4);
            As[kc * 4 + 0][row] = v.x; As[kc * 4 + 1][row] = v.y;
            As[kc * 4 + 2][row] = v.z; As[kc * 4 + 3][row] = v.w;
        }
        #pragma unroll
        for (int l = 0; l < 2; l++) {
            int f = tid + l * 256;
            int row = f >> 2, kc = f & 3;
            int n = n0 + row;
            float4 v = make_float4(0.f, 0.f, 0.f, 0.f);
            if (n < C) v = *(const float4*)(Wm + (size_t)n * DD + k0 + kc * 4);
            Bs[kc * 4 + 0][row] = v.x; Bs[kc * 4 + 1][row] = v.y;
            Bs[kc * 4 + 2][row] = v.z; Bs[kc * 4 + 3][row] = v.w;
        }
        __syncthreads();
        #pragma unroll
        for (int k = 0; k < BK; k++) {
            float4 a0 = *(const float4*)&As[k][ty * 8];
            float4 a1 = *(const float4*)&As[k][ty * 8 + 4];
            float4 b0 = *(const float4*)&Bs[k][tx * 8];
            float4 b1 = *(const float4*)&Bs[k][tx * 8 + 4];
            float a[8] = {a0.x, a0.y, a0.z, a0.w, a1.x, a1.y, a1.z, a1.w};
            float b[8] = {b0.x, b0.y, b0.z, b0.w, b1.x, b1.y, b1.z, b1.w};
            #pragma unroll
            for (int i = 0; i < 8; i++)
                #pragma unroll
                for (int j = 0; j < 8; j++) acc[i][j] = fmaf(a[i], b[j], acc[i][j]);
        }
        __syncthreads();
    }
    const bool full = (n0 + BN <= C);
    #pragma unroll
    for (int i = 0; i < 8; i++) {
        int m = m0 + ty * 8 + i;
        float* orow = out + (size_t)m * C + n0 + tx * 8;
        float s = 0.0f;
        if (full) {
            *(float4*)orow = make_float4(acc[i][0], acc[i][1], acc[i][2], acc[i][3]);
            *(float4*)(orow + 4) = make_float4(acc[i][4], acc[i][5], acc[i][6], acc[i][7]);
            #pragma unroll
            for (int j = 0; j < 8; j++) s += expf(30.0f * acc[i][j]);
        } else {
            #pragma unroll
            for (int j = 0; j < 8; j++) {
                int n = n0 + tx * 8 + j;
                if (n < C) { orow[j] = acc[i][j]; s += expf(30.0f * acc[i][j]); }
            }
        }
        #pragma unroll
        for (int off = 1; off < 16; off <<= 1) s += __shfl_xor(s, off, 64);
        if (tx == 0) atomicAdd(&sumexp[m], s);
    }
}

// ---------------- Kernel 4: per-row loss + mean ---------------------------
__global__ __launch_bounds__(1024) void arc_finalize(const float* __restrict__ cosm,
                                                     const int* __restrict__ labels,
                                                     const float* __restrict__ sumexp,
                                                     float* __restrict__ out_loss,
                                                     int B, int C) {
    int r = threadIdx.x;
    float loss = 0.0f;
    if (r < B) {
        int lab = labels[r];
        float t_raw = cosm[(size_t)r * C + lab];
        float se = sumexp[r];
        float t = fminf(fmaxf(t_raw, -1.0f + 1e-7f), 1.0f - 1e-7f);
        const float cosM = 0.9210609940028851f;
        const float sinM = 0.3894183423086505f;
        float num = 30.0f * (t * cosM - sqrtf(fmaxf(1.0f - t * t, 0.0f)) * sinM);
        float excl = se - expf(30.0f * t_raw);
        float denom = expf(num) + excl;
        loss = num - logf(denom);
    }
    __shared__ float red[1024];
    red[threadIdx.x] = loss;
    __syncthreads();
    for (int s = 512; s > 0; s >>= 1) {
        if (threadIdx.x < s) red[threadIdx.x] += red[threadIdx.x + s];
        __syncthreads();
    }
    if (threadIdx.x == 0) out_loss[0] = -red[0] / (float)B;
}

extern "C" void kernel_launch(void* const* d_in, const int* in_sizes, int n_in,
                              void* d_out, int out_size, void* d_ws, size_t ws_size,
                              hipStream_t stream) {
    const float* x = (const float*)d_in[0];
    const int* labels = (const int*)d_in[1];
    const float* Wm = (const float*)d_in[2];
    int B = in_sizes[1];
    int C = in_sizes[2] / DD;
    float* out = (float*)d_out;

    size_t need = 4096 + (size_t)B * DD * 2 + (size_t)C * DD * 2 + 256;
    if (ws_size >= need) {
        // bf16 MFMA path
        float* sumexp = (float*)d_ws;                                    // B floats (<=4KB)
        __hip_bfloat16* xnb = (__hip_bfloat16*)((char*)d_ws + 4096);     // B*DD bf16
        __hip_bfloat16* Wb = xnb + (size_t)B * DD;                       // C*DD bf16

        arc_normalize_bf16<<<B, 256, 0, stream>>>(x, xnb, sumexp, B);
        long wn = (long)C * DD;
        long nblk = (wn / 8 + 255) / 256;
        arc_cvt_w<<<(int)nblk, 256, 0, stream>>>(Wm, Wb, wn);
        dim3 grid(B / TM, (C + TN - 1) / TN);
        arc_gemm_mfma<<<grid, 256, 0, stream>>>(xnb, Wb, out, sumexp, C);
        arc_finalize<<<1, 1024, 0, stream>>>(out, labels, sumexp, out + (size_t)B * C, B, C);
    } else {
        // fp32 fallback
        float* xn = (float*)d_ws;
        float* sumexp = xn + (size_t)B * DD;
        arc_normalize_f32<<<B, 256, 0, stream>>>(x, xn, sumexp, B);
        dim3 grid(B / BM, (C + BN - 1) / BN);
        arc_gemm_f32<<<grid, 256, 0, stream>>>(xn, Wm, out, sumexp, B, C);
        arc_finalize<<<1, 1024, 0, stream>>>(out, labels, sumexp, out + (size_t)B * C, B, C);
    }
}